// Round 10
// baseline (86.007 us; speedup 1.0000x reference)
//
#include <hip/hip_runtime.h>
#include <math.h>

#define NATOMS   4096
#define NRBF     16
#define NHID     64
#define CUTOFF2  25.0f
// ETA = 0.5*(5.0-0.5)/16 = 0.140625 ; 1/(2*ETA^2)
#define INV_2ETA2 25.283950617283951f
#define PI_OVER_CUTOFF 0.62831853071795865f  // pi / 5
#define CAP      96     // per-wave neighbor capacity (mean ~33; r2/r3/r6/r9 passed)
#define CAP2     384    // per-wave candidate capacity (mean ~216, sigma ~15, +11 sigma)

// ---- cell geometry (box 40, cutoff 5 -> 8^3 cells, lambda = 8 atoms/cell) ----
#define NC1      8
#define NCELLS   512
#define INV_CELL 0.2f    // 1 / 5.0

// ws layout: [0, 4096) per-atom energies only (no global cell list anymore)
#define WS_NEED_BYTES ((size_t)(NATOMS) * 4)

// ============================ fused cell path ============================
// 2 dispatches, NO global atomics, NO cross-block sync (r3/r6 lesson: any
// 1024-block coherence protocol costs ~27us on gfx950 regardless of fan-in).
//
// Per block (4 waves = 4 atoms): block-local binning replaces the global
// cell list. Phase A: each wave sets bit `wave` of nm32[c] for its 27
// neighbor cells. Phase B: 256 threads scan all 4096 atoms once (16/thread,
// coalesced), 1 LDS mask read/atom, LDS-atomic insert of candidate positions
// into per-wave lists (~216 each). Phase C: per-wave dense sieve (4 iters of
// 64 lanes vs r9's 14 padded-cell iters), same predicate -> same pass-set.
// Then RBF/MLP verbatim from r9 (measured 80.6us total in 3-dispatch shape).
__global__ __launch_bounds__(256) void short_range_fused_kernel(
    const float* __restrict__ pos,
    const float* __restrict__ centers,
    const float* __restrict__ W1, const float* __restrict__ b1,
    const float* __restrict__ W2, const float* __restrict__ b2,
    const float* __restrict__ W3,
    float* __restrict__ ws)
{
    __shared__ unsigned int nm32[NCELLS];   // 2 KB: bit w of word c => cell c in wave w's 27-hood
    __shared__ int    ccount[4];
    __shared__ float4 scand[4][CAP2];       // 24 KB candidate positions
    __shared__ float  sdist[4][CAP];        // 1.5 KB
    __shared__ float  s_h1[4][NHID];        // 1 KB

    const int tid  = threadIdx.x;
    const int lane = tid & 63;
    const int wave = tid >> 6;
    const int i    = blockIdx.x * 4 + wave;   // this wave's atom

    const float xi = pos[3 * i + 0];
    const float yi = pos[3 * i + 1];
    const float zi = pos[3 * i + 2];
    const int cxi = min((int)(xi * INV_CELL), NC1 - 1);
    const int cyi = min((int)(yi * INV_CELL), NC1 - 1);
    const int czi = min((int)(zi * INV_CELL), NC1 - 1);

    // ---- zero masks + counters ----
    nm32[tid]       = 0u;
    nm32[tid + 256] = 0u;
    if (tid < 4) ccount[tid] = 0;
    __syncthreads();

    // ---- phase A: mark this wave's 27 neighbor cells ----
    if (lane < 27) {
        const int cx = cxi + (lane % 3) - 1;
        const int cy = cyi + ((lane / 3) % 3) - 1;
        const int cz = czi + (lane / 9) - 1;
        if ((unsigned)cx < (unsigned)NC1 && (unsigned)cy < (unsigned)NC1 &&
            (unsigned)cz < (unsigned)NC1)
            atomicOr(&nm32[(cz * NC1 + cy) * NC1 + cx], 1u << wave);
    }
    __syncthreads();

    // ---- phase B: cooperative scan of all 4096 atoms (16 per thread) ----
    {
        const float4* src = (const float4*)pos;
#pragma unroll
        for (int g = 0; g < 4; ++g) {
            const float4 v0 = src[12 * tid + 3 * g + 0];  // x0 y0 z0 x1
            const float4 v1 = src[12 * tid + 3 * g + 1];  // y1 z1 x2 y2
            const float4 v2 = src[12 * tid + 3 * g + 2];  // z2 x3 y3 z3
            const float xs[4] = {v0.x, v0.w, v1.z, v2.y};
            const float ys[4] = {v0.y, v1.x, v1.w, v2.z};
            const float zs[4] = {v0.z, v1.y, v2.x, v2.w};
#pragma unroll
            for (int u = 0; u < 4; ++u) {
                const int cx = min((int)(xs[u] * INV_CELL), NC1 - 1);
                const int cy = min((int)(ys[u] * INV_CELL), NC1 - 1);
                const int cz = min((int)(zs[u] * INV_CELL), NC1 - 1);
                const unsigned m = nm32[(cz * NC1 + cy) * NC1 + cx];
#pragma unroll
                for (int w = 0; w < 4; ++w) {
                    if ((m >> w) & 1u) {
                        const int slot = atomicAdd(&ccount[w], 1);  // LDS atomic
                        if (slot < CAP2)
                            scand[w][slot] =
                                make_float4(xs[u], ys[u], zs[u], 0.0f);
                    }
                }
            }
        }
    }
    __syncthreads();

    // ---- phase C: per-wave dense sieve; ballot + prefix compaction ----
    const int cnt = min(ccount[wave], CAP2);   // wave-uniform
    int base = 0;
    for (int j0 = 0; j0 < cnt; j0 += 64) {
        const int j = j0 + lane;
        float sq = 1e30f;
        bool pass = false;
        if (j < cnt) {
            const float4 p = scand[wave][j];
            const float dx = p.x - xi;
            const float dy = p.y - yi;
            const float dz = p.z - zi;
            sq = dx * dx + dy * dy + dz * dz;
            pass = (sq > 0.0f) && (sq < CUTOFF2);   // verbatim predicate
        }
        const unsigned long long m = __ballot(pass);
        if (pass) {
            const int slot = base + (int)__popcll(m & ((1ull << lane) - 1ull));
            if (slot < CAP) sdist[wave][slot] = sqrtf(sq);
        }
        base += (int)__popcll(m);
    }
    const int count = min(base, CAP);

    // ---- dense RBF, transposed: entry = e0 + (lane>>4), feature = lane&15 ----
    const int   kf   = lane & 15;
    const int   eoff = lane >> 4;
    const float ck   = centers[kf];
    float acc = 0.0f;
    for (int e0 = 0; e0 < count; e0 += 4) {
        const int e = e0 + eoff;
        if (e < count) {
            const float d = sdist[wave][e];
            const float w = 0.5f * (1.0f + __cosf(d * PI_OVER_CUTOFF));
            const float t = d - ck;
            acc += w * __expf(-(t * t) * INV_2ETA2);
        }
    }
    acc += __shfl_xor(acc, 16, 64);
    acc += __shfl_xor(acc, 32, 64);

    // ---- per-wave MLP: lane n owns hidden unit n (NHID == 64) ----
    float h = b1[lane];
#pragma unroll
    for (int k = 0; k < NRBF; ++k)
        h += __shfl(acc, k, 64) * W1[k * NHID + lane];   // broadcast feat[k]
    h = h / (1.0f + __expf(-h));         // silu
    s_h1[wave][lane] = h;
    // single-wave producer/consumer on own LDS row: program order suffices
    float h2 = b2[lane];
#pragma unroll 8
    for (int m = 0; m < NHID; ++m) h2 += s_h1[wave][m] * W2[m * NHID + lane];
    h2 = h2 / (1.0f + __expf(-h2));      // silu
    float e = h2 * W3[lane];
#pragma unroll
    for (int off = 32; off > 0; off >>= 1) e += __shfl_xor(e, off, 64);
    if (lane == 0) ws[i] = e;
}

// Sum 4096 per-atom energies + NATOMS*b3 -> out[0]. One block. (Verbatim r9.)
__global__ __launch_bounds__(256) void reduce4k_kernel(
    const float* __restrict__ ws, const float* __restrict__ b3,
    float* __restrict__ out)
{
    __shared__ float s_part[4];
    const int tid  = threadIdx.x;
    const int lane = tid & 63;
    const int wave = tid >> 6;

    const float4* v4 = (const float4*)ws;
    float s = 0.0f;
#pragma unroll
    for (int k = 0; k < 4; ++k) {
        const float4 v = v4[tid + 256 * k];   // 1024 float4 = 4096 floats
        s += v.x + v.y + v.z + v.w;
    }
#pragma unroll
    for (int off = 32; off > 0; off >>= 1) s += __shfl_xor(s, off, 64);
    if (lane == 0) s_part[wave] = s;
    __syncthreads();
    if (tid == 0)
        out[0] = s_part[0] + s_part[1] + s_part[2] + s_part[3]
               + (float)NATOMS * b3[0];
}

// ==================== fallback: previous verified path ====================
// (verbatim 83 us kernel; used only if ws_size < WS_NEED_BYTES)

#define CHUNK 1024

__global__ __launch_bounds__(256) void short_range_fb_kernel(
    const float* __restrict__ pos,
    const float* __restrict__ centers,
    const float* __restrict__ W1, const float* __restrict__ b1,
    const float* __restrict__ W2, const float* __restrict__ b2,
    const float* __restrict__ W3,
    float* __restrict__ ws)
{
    __shared__ float spos[3 * CHUNK];
    __shared__ float sdist[4][CAP];
    __shared__ float s_h1[4][NHID];
    __shared__ float s_part[4];

    const int tid  = threadIdx.x;
    const int lane = tid & 63;
    const int wave = tid >> 6;
    const int i    = blockIdx.x * 4 + wave;

    float* sx = spos;
    float* sy = spos + CHUNK;
    float* sz = spos + 2 * CHUNK;

    const float xi = pos[3 * i + 0];
    const float yi = pos[3 * i + 1];
    const float zi = pos[3 * i + 2];

    int base = 0;
    for (int c = 0; c < 4; ++c) {
        {
            const float4* src = (const float4*)(pos + c * (3 * CHUNK));
            const float4 v0 = src[3 * tid + 0];
            const float4 v1 = src[3 * tid + 1];
            const float4 v2 = src[3 * tid + 2];
            *(float4*)&sx[4 * tid] = make_float4(v0.x, v0.w, v1.z, v2.y);
            *(float4*)&sy[4 * tid] = make_float4(v0.y, v1.x, v1.w, v2.z);
            *(float4*)&sz[4 * tid] = make_float4(v0.z, v1.y, v2.x, v2.w);
        }
        __syncthreads();
#pragma unroll
        for (int it = 0; it < 4; ++it) {
            const int a = it * 256 + lane * 4;
            const float4 vx = *(const float4*)&sx[a];
            const float4 vy = *(const float4*)&sy[a];
            const float4 vz = *(const float4*)&sz[a];
#pragma unroll
            for (int u = 0; u < 4; ++u) {
                const float dx = ((const float*)&vx)[u] - xi;
                const float dy = ((const float*)&vy)[u] - yi;
                const float dz = ((const float*)&vz)[u] - zi;
                const float sq = dx * dx + dy * dy + dz * dz;
                const bool pass = (sq > 0.0f) && (sq < CUTOFF2);
                const unsigned long long mask = __ballot(pass);
                if (pass) {
                    const int slot = base + (int)__popcll(mask & ((1ull << lane) - 1ull));
                    if (slot < CAP) sdist[wave][slot] = sqrtf(sq);
                }
                base += (int)__popcll(mask);
            }
        }
        __syncthreads();
    }
    const int count = min(base, CAP);

    const int   kf   = lane & 15;
    const int   eoff = lane >> 4;
    const float ck   = centers[kf];
    float acc = 0.0f;
    for (int e0 = 0; e0 < count; e0 += 4) {
        const int e = e0 + eoff;
        if (e < count) {
            const float d = sdist[wave][e];
            const float w = 0.5f * (1.0f + __cosf(d * PI_OVER_CUTOFF));
            const float t = d - ck;
            acc += w * __expf(-(t * t) * INV_2ETA2);
        }
    }
    acc += __shfl_xor(acc, 16, 64);
    acc += __shfl_xor(acc, 32, 64);

    float h = b1[lane];
#pragma unroll
    for (int k = 0; k < NRBF; ++k)
        h += __shfl(acc, k, 64) * W1[k * NHID + lane];
    h = h / (1.0f + __expf(-h));
    s_h1[wave][lane] = h;
    float h2 = b2[lane];
#pragma unroll 8
    for (int m = 0; m < NHID; ++m) h2 += s_h1[wave][m] * W2[m * NHID + lane];
    h2 = h2 / (1.0f + __expf(-h2));
    float e = h2 * W3[lane];
#pragma unroll
    for (int off = 32; off > 0; off >>= 1) e += __shfl_xor(e, off, 64);
    if (lane == 0) s_part[wave] = e;
    __syncthreads();
    if (tid == 0)
        ws[blockIdx.x] = s_part[0] + s_part[1] + s_part[2] + s_part[3];
}

__global__ __launch_bounds__(256) void reduce_fb_kernel(
    const float* __restrict__ ws, const float* __restrict__ b3,
    float* __restrict__ out)
{
    __shared__ float s_part[4];
    const int tid  = threadIdx.x;
    const int lane = tid & 63;
    const int wave = tid >> 6;

    const float4 v = ((const float4*)ws)[tid];
    float s = v.x + v.y + v.z + v.w;
#pragma unroll
    for (int off = 32; off > 0; off >>= 1) s += __shfl_xor(s, off, 64);
    if (lane == 0) s_part[wave] = s;
    __syncthreads();
    if (tid == 0)
        out[0] = s_part[0] + s_part[1] + s_part[2] + s_part[3]
               + (float)NATOMS * b3[0];
}

// ============================== launch ==============================

extern "C" void kernel_launch(void* const* d_in, const int* in_sizes, int n_in,
                              void* d_out, int out_size, void* d_ws, size_t ws_size,
                              hipStream_t stream) {
    const float* pos     = (const float*)d_in[0];
    const float* centers = (const float*)d_in[1];
    const float* W1      = (const float*)d_in[2];
    const float* b1      = (const float*)d_in[3];
    const float* W2      = (const float*)d_in[4];
    const float* b2      = (const float*)d_in[5];
    const float* W3      = (const float*)d_in[6];
    const float* b3      = (const float*)d_in[7];
    float* out = (float*)d_out;
    float* ws  = (float*)d_ws;

    if (ws_size >= WS_NEED_BYTES) {
        hipLaunchKernelGGL(short_range_fused_kernel, dim3(NATOMS / 4), dim3(256), 0, stream,
                           pos, centers, W1, b1, W2, b2, W3, ws);
        hipLaunchKernelGGL(reduce4k_kernel, dim3(1), dim3(256), 0, stream,
                           ws, b3, out);
    } else {
        // workspace too small: previous verified path
        hipLaunchKernelGGL(short_range_fb_kernel, dim3(NATOMS / 4), dim3(256), 0, stream,
                           pos, centers, W1, b1, W2, b2, W3, ws);
        hipLaunchKernelGGL(reduce_fb_kernel, dim3(1), dim3(256), 0, stream,
                           ws, b3, out);
    }
}

// Round 11
// 82.379 us; speedup vs baseline: 1.0440x; 1.0440x over previous
//
#include <hip/hip_runtime.h>
#include <math.h>

#define NATOMS   4096
#define NRBF     16
#define NHID     64
#define CUTOFF2  25.0f
// ETA = 0.5*(5.0-0.5)/16 = 0.140625 ; 1/(2*ETA^2)
#define INV_2ETA2 25.283950617283951f
#define PI_OVER_CUTOFF 0.62831853071795865f  // pi / 5
#define CAP      96     // per-wave neighbor capacity (mean ~33; r2..r10 passed)
#define SEGCAP   128    // per (target,producer) candidate segment (mean ~54, +10 sigma)

// ---- cell geometry (box 40, cutoff 5 -> 8^3 cells, lambda = 8 atoms/cell) ----
#define NC1      8
#define NCELLS   512
#define INV_CELL 0.2f    // 1 / 5.0

// ws layout: [0, 4096) per-atom energies only
#define WS_NEED_BYTES ((size_t)(NATOMS) * 4)

// ============================ fused cell path (v2) ============================
// 2 dispatches, NO global atomics, NO cross-block sync, and now NO LDS atomics
// in the scan (r10 lesson: 864 inserts/block through 4 shared counters
// serialize ~5K cyc/block = ~13us aggregate; r3/r6/r10 all convicted
// same-address RMW).  Phase B uses the same wave-ballot prefix compaction the
// sieve has used (measured cheap) since r2: candidate lists are partitioned by
// producer wave -> insert counters are wave-uniform REGISTERS.
__global__ __launch_bounds__(256) void short_range_fused_kernel(
    const float* __restrict__ pos,
    const float* __restrict__ centers,
    const float* __restrict__ W1, const float* __restrict__ b1,
    const float* __restrict__ W2, const float* __restrict__ b2,
    const float* __restrict__ W3,
    float* __restrict__ ws)
{
    __shared__ unsigned int nm32[NCELLS];        // 2 KB: bit w of word c => cell c in wave w's 27-hood
    __shared__ float4 seg[4][4][SEGCAP];         // 32 KB: [target][producer] candidate positions
    __shared__ int    scnt[4][4];                // [target][producer] counts
    __shared__ float  sdist[4][CAP];             // 1.5 KB
    __shared__ float  s_h1[4][NHID];             // 1 KB

    const int tid  = threadIdx.x;
    const int lane = tid & 63;
    const int wave = tid >> 6;
    const int i    = blockIdx.x * 4 + wave;   // this wave's atom

    const float xi = pos[3 * i + 0];
    const float yi = pos[3 * i + 1];
    const float zi = pos[3 * i + 2];
    const int cxi = min((int)(xi * INV_CELL), NC1 - 1);
    const int cyi = min((int)(yi * INV_CELL), NC1 - 1);
    const int czi = min((int)(zi * INV_CELL), NC1 - 1);

    // ---- zero neighbor masks ----
    nm32[tid]       = 0u;
    nm32[tid + 256] = 0u;
    __syncthreads();

    // ---- phase A: mark this wave's 27 neighbor cells (few, disjoint-ish) ----
    if (lane < 27) {
        const int cx = cxi + (lane % 3) - 1;
        const int cy = cyi + ((lane / 3) % 3) - 1;
        const int cz = czi + (lane / 9) - 1;
        if ((unsigned)cx < (unsigned)NC1 && (unsigned)cy < (unsigned)NC1 &&
            (unsigned)cz < (unsigned)NC1)
            atomicOr(&nm32[(cz * NC1 + cy) * NC1 + cx], 1u << wave);
    }
    __syncthreads();

    // ---- phase B: cooperative scan, ballot-compacted insert (NO atomics) ----
    // Thread t handles atoms 16t..16t+15; wave p covers [1024p, 1024p+1024).
    // Counters bs[0..3] are wave-uniform registers (ballot popcounts).
    {
        const float4* src = (const float4*)pos;
        int bs[4] = {0, 0, 0, 0};
#pragma unroll
        for (int g = 0; g < 4; ++g) {
            const float4 v0 = src[12 * tid + 3 * g + 0];  // x0 y0 z0 x1
            const float4 v1 = src[12 * tid + 3 * g + 1];  // y1 z1 x2 y2
            const float4 v2 = src[12 * tid + 3 * g + 2];  // z2 x3 y3 z3
            const float xs[4] = {v0.x, v0.w, v1.z, v2.y};
            const float ys[4] = {v0.y, v1.x, v1.w, v2.z};
            const float zs[4] = {v0.z, v1.y, v2.x, v2.w};
#pragma unroll
            for (int u = 0; u < 4; ++u) {
                const int cx = min((int)(xs[u] * INV_CELL), NC1 - 1);
                const int cy = min((int)(ys[u] * INV_CELL), NC1 - 1);
                const int cz = min((int)(zs[u] * INV_CELL), NC1 - 1);
                const unsigned m = nm32[(cz * NC1 + cy) * NC1 + cx];
#pragma unroll
                for (int w = 0; w < 4; ++w) {
                    const bool want = (m >> w) & 1u;
                    const unsigned long long bm = __ballot(want);
                    if (want) {
                        const int slot =
                            bs[w] + (int)__popcll(bm & ((1ull << lane) - 1ull));
                        if (slot < SEGCAP)
                            seg[w][wave][slot] =
                                make_float4(xs[u], ys[u], zs[u], 0.0f);
                    }
                    bs[w] += (int)__popcll(bm);
                }
            }
        }
        if (lane == 0) {
#pragma unroll
            for (int w = 0; w < 4; ++w) scnt[w][wave] = bs[w];
        }
    }
    __syncthreads();

    // ---- phase C: per-wave dense sieve over 4 segments; ballot compaction ----
    int base = 0;
#pragma unroll
    for (int p = 0; p < 4; ++p) {
        const int cn = min(scnt[wave][p], SEGCAP);   // wave-uniform
        for (int j0 = 0; j0 < cn; j0 += 64) {
            const int j = j0 + lane;
            float sq = 1e30f;
            bool pass = false;
            if (j < cn) {
                const float4 q = seg[wave][p][j];
                const float dx = q.x - xi;
                const float dy = q.y - yi;
                const float dz = q.z - zi;
                sq = dx * dx + dy * dy + dz * dz;
                pass = (sq > 0.0f) && (sq < CUTOFF2);   // verbatim predicate
            }
            const unsigned long long m2 = __ballot(pass);
            if (pass) {
                const int slot = base + (int)__popcll(m2 & ((1ull << lane) - 1ull));
                if (slot < CAP) sdist[wave][slot] = sqrtf(sq);
            }
            base += (int)__popcll(m2);
        }
    }
    const int count = min(base, CAP);

    // ---- dense RBF, transposed: entry = e0 + (lane>>4), feature = lane&15 ----
    const int   kf   = lane & 15;
    const int   eoff = lane >> 4;
    const float ck   = centers[kf];
    float acc = 0.0f;
    for (int e0 = 0; e0 < count; e0 += 4) {
        const int e = e0 + eoff;
        if (e < count) {
            const float d = sdist[wave][e];
            const float w = 0.5f * (1.0f + __cosf(d * PI_OVER_CUTOFF));
            const float t = d - ck;
            acc += w * __expf(-(t * t) * INV_2ETA2);
        }
    }
    acc += __shfl_xor(acc, 16, 64);
    acc += __shfl_xor(acc, 32, 64);

    // ---- per-wave MLP: lane n owns hidden unit n (NHID == 64) ----
    float h = b1[lane];
#pragma unroll
    for (int k = 0; k < NRBF; ++k)
        h += __shfl(acc, k, 64) * W1[k * NHID + lane];   // broadcast feat[k]
    h = h / (1.0f + __expf(-h));         // silu
    s_h1[wave][lane] = h;
    // single-wave producer/consumer on own LDS row: program order suffices
    float h2 = b2[lane];
#pragma unroll 8
    for (int m = 0; m < NHID; ++m) h2 += s_h1[wave][m] * W2[m * NHID + lane];
    h2 = h2 / (1.0f + __expf(-h2));      // silu
    float e = h2 * W3[lane];
#pragma unroll
    for (int off = 32; off > 0; off >>= 1) e += __shfl_xor(e, off, 64);
    if (lane == 0) ws[i] = e;
}

// Sum 4096 per-atom energies + NATOMS*b3 -> out[0]. One block. (Verbatim r9.)
__global__ __launch_bounds__(256) void reduce4k_kernel(
    const float* __restrict__ ws, const float* __restrict__ b3,
    float* __restrict__ out)
{
    __shared__ float s_part[4];
    const int tid  = threadIdx.x;
    const int lane = tid & 63;
    const int wave = tid >> 6;

    const float4* v4 = (const float4*)ws;
    float s = 0.0f;
#pragma unroll
    for (int k = 0; k < 4; ++k) {
        const float4 v = v4[tid + 256 * k];   // 1024 float4 = 4096 floats
        s += v.x + v.y + v.z + v.w;
    }
#pragma unroll
    for (int off = 32; off > 0; off >>= 1) s += __shfl_xor(s, off, 64);
    if (lane == 0) s_part[wave] = s;
    __syncthreads();
    if (tid == 0)
        out[0] = s_part[0] + s_part[1] + s_part[2] + s_part[3]
               + (float)NATOMS * b3[0];
}

// ==================== fallback: previous verified path ====================
// (verbatim 83 us kernel; used only if ws_size < WS_NEED_BYTES)

#define CHUNK 1024

__global__ __launch_bounds__(256) void short_range_fb_kernel(
    const float* __restrict__ pos,
    const float* __restrict__ centers,
    const float* __restrict__ W1, const float* __restrict__ b1,
    const float* __restrict__ W2, const float* __restrict__ b2,
    const float* __restrict__ W3,
    float* __restrict__ ws)
{
    __shared__ float spos[3 * CHUNK];
    __shared__ float sdist[4][CAP];
    __shared__ float s_h1[4][NHID];
    __shared__ float s_part[4];

    const int tid  = threadIdx.x;
    const int lane = tid & 63;
    const int wave = tid >> 6;
    const int i    = blockIdx.x * 4 + wave;

    float* sx = spos;
    float* sy = spos + CHUNK;
    float* sz = spos + 2 * CHUNK;

    const float xi = pos[3 * i + 0];
    const float yi = pos[3 * i + 1];
    const float zi = pos[3 * i + 2];

    int base = 0;
    for (int c = 0; c < 4; ++c) {
        {
            const float4* src = (const float4*)(pos + c * (3 * CHUNK));
            const float4 v0 = src[3 * tid + 0];
            const float4 v1 = src[3 * tid + 1];
            const float4 v2 = src[3 * tid + 2];
            *(float4*)&sx[4 * tid] = make_float4(v0.x, v0.w, v1.z, v2.y);
            *(float4*)&sy[4 * tid] = make_float4(v0.y, v1.x, v1.w, v2.z);
            *(float4*)&sz[4 * tid] = make_float4(v0.z, v1.y, v2.x, v2.w);
        }
        __syncthreads();
#pragma unroll
        for (int it = 0; it < 4; ++it) {
            const int a = it * 256 + lane * 4;
            const float4 vx = *(const float4*)&sx[a];
            const float4 vy = *(const float4*)&sy[a];
            const float4 vz = *(const float4*)&sz[a];
#pragma unroll
            for (int u = 0; u < 4; ++u) {
                const float dx = ((const float*)&vx)[u] - xi;
                const float dy = ((const float*)&vy)[u] - yi;
                const float dz = ((const float*)&vz)[u] - zi;
                const float sq = dx * dx + dy * dy + dz * dz;
                const bool pass = (sq > 0.0f) && (sq < CUTOFF2);
                const unsigned long long mask = __ballot(pass);
                if (pass) {
                    const int slot = base + (int)__popcll(mask & ((1ull << lane) - 1ull));
                    if (slot < CAP) sdist[wave][slot] = sqrtf(sq);
                }
                base += (int)__popcll(mask);
            }
        }
        __syncthreads();
    }
    const int count = min(base, CAP);

    const int   kf   = lane & 15;
    const int   eoff = lane >> 4;
    const float ck   = centers[kf];
    float acc = 0.0f;
    for (int e0 = 0; e0 < count; e0 += 4) {
        const int e = e0 + eoff;
        if (e < count) {
            const float d = sdist[wave][e];
            const float w = 0.5f * (1.0f + __cosf(d * PI_OVER_CUTOFF));
            const float t = d - ck;
            acc += w * __expf(-(t * t) * INV_2ETA2);
        }
    }
    acc += __shfl_xor(acc, 16, 64);
    acc += __shfl_xor(acc, 32, 64);

    float h = b1[lane];
#pragma unroll
    for (int k = 0; k < NRBF; ++k)
        h += __shfl(acc, k, 64) * W1[k * NHID + lane];
    h = h / (1.0f + __expf(-h));
    s_h1[wave][lane] = h;
    float h2 = b2[lane];
#pragma unroll 8
    for (int m = 0; m < NHID; ++m) h2 += s_h1[wave][m] * W2[m * NHID + lane];
    h2 = h2 / (1.0f + __expf(-h2));
    float e = h2 * W3[lane];
#pragma unroll
    for (int off = 32; off > 0; off >>= 1) e += __shfl_xor(e, off, 64);
    if (lane == 0) s_part[wave] = e;
    __syncthreads();
    if (tid == 0)
        ws[blockIdx.x] = s_part[0] + s_part[1] + s_part[2] + s_part[3];
}

__global__ __launch_bounds__(256) void reduce_fb_kernel(
    const float* __restrict__ ws, const float* __restrict__ b3,
    float* __restrict__ out)
{
    __shared__ float s_part[4];
    const int tid  = threadIdx.x;
    const int lane = tid & 63;
    const int wave = tid >> 6;

    const float4 v = ((const float4*)ws)[tid];
    float s = v.x + v.y + v.z + v.w;
#pragma unroll
    for (int off = 32; off > 0; off >>= 1) s += __shfl_xor(s, off, 64);
    if (lane == 0) s_part[wave] = s;
    __syncthreads();
    if (tid == 0)
        out[0] = s_part[0] + s_part[1] + s_part[2] + s_part[3]
               + (float)NATOMS * b3[0];
}

// ============================== launch ==============================

extern "C" void kernel_launch(void* const* d_in, const int* in_sizes, int n_in,
                              void* d_out, int out_size, void* d_ws, size_t ws_size,
                              hipStream_t stream) {
    const float* pos     = (const float*)d_in[0];
    const float* centers = (const float*)d_in[1];
    const float* W1      = (const float*)d_in[2];
    const float* b1      = (const float*)d_in[3];
    const float* W2      = (const float*)d_in[4];
    const float* b2      = (const float*)d_in[5];
    const float* W3      = (const float*)d_in[6];
    const float* b3      = (const float*)d_in[7];
    float* out = (float*)d_out;
    float* ws  = (float*)d_ws;

    if (ws_size >= WS_NEED_BYTES) {
        hipLaunchKernelGGL(short_range_fused_kernel, dim3(NATOMS / 4), dim3(256), 0, stream,
                           pos, centers, W1, b1, W2, b2, W3, ws);
        hipLaunchKernelGGL(reduce4k_kernel, dim3(1), dim3(256), 0, stream,
                           ws, b3, out);
    } else {
        // workspace too small: previous verified path
        hipLaunchKernelGGL(short_range_fb_kernel, dim3(NATOMS / 4), dim3(256), 0, stream,
                           pos, centers, W1, b1, W2, b2, W3, ws);
        hipLaunchKernelGGL(reduce_fb_kernel, dim3(1), dim3(256), 0, stream,
                           ws, b3, out);
    }
}